// Round 7
// baseline (178.459 us; speedup 1.0000x reference)
//
#include <hip/hip_runtime.h>
#include <cfloat>
#include <math.h>

#define N_OBJ 8
#define N_PTS 2048
#define KNN   10
#define TOLC  0.01f
#define TPB   256
#define NW    4                 // waves per block = q-split factor
#define QC    (N_PTS / NW)      // 512 q's per wave
#define PC2   128               // points per block (2 per lane)
#define NCHUNK2 (N_PTS / PC2)   // 16 point-chunks per pair

// ---- order-preserving float <-> uint for atomicMin on signed floats ----
__device__ __forceinline__ unsigned int enc_f(float f) {
    unsigned int u = __float_as_uint(f);
    return (u & 0x80000000u) ? ~u : (u | 0x80000000u);
}
__device__ __forceinline__ float dec_f(unsigned int e) {
    unsigned int u = (e & 0x80000000u) ? (e & 0x7fffffffu) : ~e;
    return __uint_as_float(u);
}

// Kernel 1: per-point transform (4x4 inverse redundantly in double — closer
// to the numpy reference than fp32 adjugate; trivial cost at 64 waves).
// Writes P4=(x,y,z,|x|^2), N4=(nx,ny,nz,dot(n,x)), SD seed = enc(z).
__global__ void k_transform(const float* __restrict__ pts,
                            const float* __restrict__ T_est,
                            const float* __restrict__ T_plane,
                            float4* __restrict__ P4g,
                            float4* __restrict__ N4g,
                            unsigned int* __restrict__ SD) {
    int gid = blockIdx.x * blockDim.x + threadIdx.x;
    if (gid >= N_OBJ * N_PTS) return;
    int b = gid >> 11;

    double m[16];
#pragma unroll
    for (int i = 0; i < 16; i++) m[i] = (double)T_plane[i];
    double inv[16];
    inv[0]  =  m[5]*m[10]*m[15] - m[5]*m[11]*m[14] - m[9]*m[6]*m[15] + m[9]*m[7]*m[14] + m[13]*m[6]*m[11] - m[13]*m[7]*m[10];
    inv[4]  = -m[4]*m[10]*m[15] + m[4]*m[11]*m[14] + m[8]*m[6]*m[15] - m[8]*m[7]*m[14] - m[12]*m[6]*m[11] + m[12]*m[7]*m[10];
    inv[8]  =  m[4]*m[9]*m[15]  - m[4]*m[11]*m[13] - m[8]*m[5]*m[15] + m[8]*m[7]*m[13] + m[12]*m[5]*m[11] - m[12]*m[7]*m[9];
    inv[12] = -m[4]*m[9]*m[14]  + m[4]*m[10]*m[13] + m[8]*m[5]*m[14] - m[8]*m[6]*m[13] - m[12]*m[5]*m[10] + m[12]*m[6]*m[9];
    inv[1]  = -m[1]*m[10]*m[15] + m[1]*m[11]*m[14] + m[9]*m[2]*m[15] - m[9]*m[3]*m[14] - m[13]*m[2]*m[11] + m[13]*m[3]*m[10];
    inv[5]  =  m[0]*m[10]*m[15] - m[0]*m[11]*m[14] - m[8]*m[2]*m[15] + m[8]*m[3]*m[14] + m[12]*m[2]*m[11] - m[12]*m[3]*m[10];
    inv[9]  = -m[0]*m[9]*m[15]  + m[0]*m[11]*m[13] + m[8]*m[1]*m[15] - m[8]*m[3]*m[13] - m[12]*m[1]*m[11] + m[12]*m[3]*m[9];
    inv[13] =  m[0]*m[9]*m[14]  - m[0]*m[10]*m[13] - m[8]*m[1]*m[14] + m[8]*m[2]*m[13] + m[12]*m[1]*m[10] - m[12]*m[2]*m[9];
    inv[2]  =  m[1]*m[6]*m[15]  - m[1]*m[7]*m[14]  - m[5]*m[2]*m[15] + m[5]*m[3]*m[14] + m[13]*m[2]*m[7]  - m[13]*m[3]*m[6];
    inv[6]  = -m[0]*m[6]*m[15]  + m[0]*m[7]*m[14]  + m[4]*m[2]*m[15] - m[4]*m[3]*m[14] - m[12]*m[2]*m[7]  + m[12]*m[3]*m[6];
    inv[10] =  m[0]*m[5]*m[15]  - m[0]*m[7]*m[13]  - m[4]*m[1]*m[15] + m[4]*m[3]*m[13] + m[12]*m[1]*m[7]  - m[12]*m[3]*m[5];
    inv[14] = -m[0]*m[5]*m[14]  + m[0]*m[6]*m[13]  + m[4]*m[1]*m[14] - m[4]*m[2]*m[13] - m[12]*m[1]*m[6]  + m[12]*m[2]*m[5];
    inv[3]  = -m[1]*m[6]*m[11]  + m[1]*m[7]*m[10]  + m[5]*m[2]*m[11] - m[5]*m[3]*m[10] - m[9]*m[2]*m[7]   + m[9]*m[3]*m[6];
    inv[7]  =  m[0]*m[6]*m[11]  - m[0]*m[7]*m[10]  - m[4]*m[2]*m[11] + m[4]*m[3]*m[10] + m[8]*m[2]*m[7]   - m[8]*m[3]*m[6];
    inv[11] = -m[0]*m[5]*m[11]  + m[0]*m[7]*m[9]   + m[4]*m[1]*m[11] - m[4]*m[3]*m[9]  - m[8]*m[1]*m[7]   + m[8]*m[3]*m[5];
    inv[15] =  m[0]*m[5]*m[10]  - m[0]*m[6]*m[9]   - m[4]*m[1]*m[10] + m[4]*m[2]*m[9]  + m[8]*m[1]*m[6]   - m[8]*m[2]*m[5];
    double det  = m[0]*inv[0] + m[1]*inv[4] + m[2]*inv[8] + m[3]*inv[12];
    double rdet = 1.0 / det;

    const float* Te = T_est + b * 16;
    double M[12];
#pragma unroll
    for (int i = 0; i < 3; i++)
#pragma unroll
        for (int j = 0; j < 4; j++) {
            double s = 0.0;
#pragma unroll
            for (int kk = 0; kk < 4; kk++) s += inv[i*4+kk] * rdet * (double)Te[kk*4+j];
            M[i*4+j] = s;
        }

    const float* pp = pts + (size_t)gid * 6;
    double px = pp[0], py = pp[1], pz = pp[2];
    float nx = pp[3], ny = pp[4], nz = pp[5];
    float x = (float)(M[0]*px + M[1]*py + M[2]*pz  + M[3]);
    float y = (float)(M[4]*px + M[5]*py + M[6]*pz  + M[7]);
    float z = (float)(M[8]*px + M[9]*py + M[10]*pz + M[11]);
    float sq = fmaf(x, x, fmaf(y, y, z * z));
    float w  = fmaf(nx, x, fmaf(ny, y, nz * z));
    P4g[gid] = make_float4(x, y, z, sq);
    N4g[gid] = make_float4(nx, ny, nz, w);
    SD[gid]  = enc_f(z);   // seed min with the plane-distance term z
}

// One q against TWO points per lane: 44 VALU ops. Per-p op order is IDENTICAL
// to rounds 0-6 (bit-identical numerics); the p0/p1 chains are interleaved for
// ILP. Q data comes from SGPRs (broadcast, shared by both p's); <=1 SGPR per
// VALU inst (SGPR in src0 for VOP2, src1 for VOP3 fma).
#define QB2(PX,PY,PZ,PW,NX,NY,NZ,NWW) \
  "v_mul_f32 %[t0], " PZ ", %[mz0]\n" \
  "v_mul_f32 %[t2], " PZ ", %[mz1]\n" \
  "v_fma_f32 %[t0], %[my0], " PY ", %[t0]\n" \
  "v_fma_f32 %[t2], %[my1], " PY ", %[t2]\n" \
  "v_fma_f32 %[t0], %[mx0], " PX ", %[t0]\n" \
  "v_fma_f32 %[t2], %[mx1], " PX ", %[t2]\n" \
  "v_add_f32 %[t0], " PW ", %[t0]\n" \
  "v_add_f32 %[t2], " PW ", %[t2]\n" \
  "v_mul_f32 %[t1], " NZ ", %[gz0]\n" \
  "v_mul_f32 %[t3], " NZ ", %[gz1]\n" \
  "v_fma_f32 %[t1], %[gy0], " NY ", %[t1]\n" \
  "v_fma_f32 %[t3], %[gy1], " NY ", %[t3]\n" \
  "v_fma_f32 %[t1], %[gx0], " NX ", %[t1]\n" \
  "v_fma_f32 %[t3], %[gx1], " NX ", %[t3]\n" \
  "v_add_f32 %[t1], " NWW ", %[t1]\n" \
  "v_add_f32 %[t3], " NWW ", %[t3]\n" \
  "v_and_b32 %[t0], -2, %[t0]\n" \
  "v_and_b32 %[t2], -2, %[t2]\n" \
  "v_cmp_lt_f32 vcc, 0, %[t1]\n" \
  "v_cndmask_b32_e64 %[t1], 0, 1, vcc\n" \
  "v_or_b32 %[t0], %[t0], %[t1]\n" \
  "v_cmp_lt_f32 vcc, 0, %[t3]\n" \
  "v_cndmask_b32_e64 %[t3], 0, 1, vcc\n" \
  "v_or_b32 %[t2], %[t2], %[t3]\n" \
  "v_med3_f32 %[d9], %[d8], %[d9], %[t0]\n" \
  "v_med3_f32 %[d8], %[d7], %[d8], %[t0]\n" \
  "v_med3_f32 %[d7], %[d6], %[d7], %[t0]\n" \
  "v_med3_f32 %[d6], %[d5], %[d6], %[t0]\n" \
  "v_med3_f32 %[d5], %[d4], %[d5], %[t0]\n" \
  "v_med3_f32 %[d4], %[d3], %[d4], %[t0]\n" \
  "v_med3_f32 %[d3], %[d2], %[d3], %[t0]\n" \
  "v_med3_f32 %[d2], %[d1], %[d2], %[t0]\n" \
  "v_med3_f32 %[d1], %[d0], %[d1], %[t0]\n" \
  "v_min_f32 %[d0], %[d0], %[t0]\n" \
  "v_med3_f32 %[e9], %[e8], %[e9], %[t2]\n" \
  "v_med3_f32 %[e8], %[e7], %[e8], %[t2]\n" \
  "v_med3_f32 %[e7], %[e6], %[e7], %[t2]\n" \
  "v_med3_f32 %[e6], %[e5], %[e6], %[t2]\n" \
  "v_med3_f32 %[e5], %[e4], %[e5], %[t2]\n" \
  "v_med3_f32 %[e4], %[e3], %[e4], %[t2]\n" \
  "v_med3_f32 %[e3], %[e2], %[e3], %[t2]\n" \
  "v_med3_f32 %[e2], %[e1], %[e2], %[t2]\n" \
  "v_med3_f32 %[e1], %[e0], %[e1], %[t2]\n" \
  "v_min_f32 %[e0], %[e0], %[t2]\n"

// Kernel 2 v7: r4's pure-SMEM double-banked structure + 2 points per lane.
// The SGPR q-broadcast is shared by all lanes AND both per-lane points, so:
//   - SMEM demand halves vs r4: 3584 lines/CU -> ~57us supply < ~66-75us
//     VALU floor (r4 was line-bound at 7168 lines = its 115us wall)
//   - per-bank compute doubles to 352cy own-issue -> 2x the latency cover at
//     each full lgkmcnt(0) drain (SMEM completes OOO; only full drains safe)
// Per-(p,q) VALU is unchanged (44/q for 2 p) -> floor ~66us/SIMD balanced,
// ~75us on critical CUs (grid 896 = 3.5 blocks/CU, ~12% tail — the price of
// PC=128; q must NOT be split across blocks: the inside-vote over the true
// top-10 is not decomposable through atomicMin).
__global__ void __launch_bounds__(TPB, 7) k_pairs(const float4* __restrict__ P4g,
                                                  const float4* __restrict__ N4g,
                                                  unsigned int* __restrict__ SD) {
    // stride 11 floats: 11 coprime 32 -> 2 lanes/bank, conflict-free. 22528B.
    __shared__ float MRG[NW][PC2][KNN + 1];

    int bx    = blockIdx.x;
    int pair  = bx >> 4;           // / NCHUNK2
    int chunk = bx & (NCHUNK2 - 1);
    int b  = pair / 7;
    int oi = pair % 7;
    int o  = oi + (oi >= b ? 1 : 0);
    int tid  = threadIdx.x;
    int lane = tid & 63;
    int wu   = __builtin_amdgcn_readfirstlane(tid >> 6);
    int p0   = chunk * PC2 + lane;
    int p1   = p0 + 64;

    float4 xp0 = P4g[b * N_PTS + p0];        // (x, y, z, sq_p)
    float4 xp1 = P4g[b * N_PTS + p1];
    float mx0 = -2.0f * xp0.x, my0 = -2.0f * xp0.y, mz0 = -2.0f * xp0.z;
    float gx0 = -xp0.x, gy0 = -xp0.y, gz0 = -xp0.z;
    float mx1 = -2.0f * xp1.x, my1 = -2.0f * xp1.y, mz1 = -2.0f * xp1.z;
    float gx1 = -xp1.x, gy1 = -xp1.y, gz1 = -xp1.z;

    const float4* Po = P4g + o * N_PTS + wu * QC;   // uniform stream bases
    const float4* No = N4g + o * N_PTS + wu * QC;
    unsigned long long ap = (unsigned long long)(uintptr_t)Po;
    unsigned long long an = (unsigned long long)(uintptr_t)No;

    const float FMAXE = __uint_as_float(0x7F7FFFFEu);   // FLT_MAX, LSB clear
    float d0_ = FMAXE, d1_ = FMAXE, d2_ = FMAXE, d3_ = FMAXE, d4_ = FMAXE;
    float d5_ = FMAXE, d6_ = FMAXE, d7_ = FMAXE, d8_ = FMAXE, d9_ = FMAXE;
    float e0_ = FMAXE, e1_ = FMAXE, e2_ = FMAXE, e3_ = FMAXE, e4_ = FMAXE;
    float e5_ = FMAXE, e6_ = FMAXE, e7_ = FMAXE, e8_ = FMAXE, e9_ = FMAXE;
    float t0, t1, t2, t3;

    // Double-banked SGPR q-buffers: bank A s[36:67] (P s[36:51], N s[52:67]),
    // bank B s[68:99]. 4 q per bank. 64 iters x 8 q = 512 q.
    // Last prefetch reads <=64B past the window: stays inside P4|N4|SD.
    asm volatile(
        "s_mov_b64 s[32:33], %[ap]\n"
        "s_mov_b64 s[34:35], %[an]\n"
        "s_load_dwordx16 s[36:51], s[32:33], 0x0\n"
        "s_load_dwordx16 s[52:67], s[34:35], 0x0\n"
        "s_mov_b32 s30, 0\n"
        "Lkp%=:\n"
        "s_waitcnt lgkmcnt(0)\n"                         // bank A ready
        "s_load_dwordx16 s[68:83], s[32:33], 0x40\n"     // prefetch bank B
        "s_load_dwordx16 s[84:99], s[34:35], 0x40\n"
        QB2("s36","s37","s38","s39","s52","s53","s54","s55")
        QB2("s40","s41","s42","s43","s56","s57","s58","s59")
        QB2("s44","s45","s46","s47","s60","s61","s62","s63")
        QB2("s48","s49","s50","s51","s64","s65","s66","s67")
        "s_waitcnt lgkmcnt(0)\n"                         // bank B ready
        "s_load_dwordx16 s[36:51], s[32:33], 0x80\n"     // prefetch next A
        "s_load_dwordx16 s[52:67], s[34:35], 0x80\n"
        QB2("s68","s69","s70","s71","s84","s85","s86","s87")
        QB2("s72","s73","s74","s75","s88","s89","s90","s91")
        QB2("s76","s77","s78","s79","s92","s93","s94","s95")
        QB2("s80","s81","s82","s83","s96","s97","s98","s99")
        "s_add_u32 s32, s32, 0x80\n"
        "s_addc_u32 s33, s33, 0\n"
        "s_add_u32 s34, s34, 0x80\n"
        "s_addc_u32 s35, s35, 0\n"
        "s_add_u32 s30, s30, 1\n"
        "s_cmp_lt_u32 s30, 64\n"
        "s_cbranch_scc1 Lkp%=\n"
        "s_waitcnt lgkmcnt(0)\n"   // drain dangling prefetch before reg reuse
        : [d0]"+v"(d0_), [d1]"+v"(d1_), [d2]"+v"(d2_), [d3]"+v"(d3_),
          [d4]"+v"(d4_), [d5]"+v"(d5_), [d6]"+v"(d6_), [d7]"+v"(d7_),
          [d8]"+v"(d8_), [d9]"+v"(d9_),
          [e0]"+v"(e0_), [e1]"+v"(e1_), [e2]"+v"(e2_), [e3]"+v"(e3_),
          [e4]"+v"(e4_), [e5]"+v"(e5_), [e6]"+v"(e6_), [e7]"+v"(e7_),
          [e8]"+v"(e8_), [e9]"+v"(e9_),
          [t0]"=&v"(t0), [t1]"=&v"(t1), [t2]"=&v"(t2), [t3]"=&v"(t3)
        : [mx0]"v"(mx0), [my0]"v"(my0), [mz0]"v"(mz0),
          [gx0]"v"(gx0), [gy0]"v"(gy0), [gz0]"v"(gz0),
          [mx1]"v"(mx1), [my1]"v"(my1), [mz1]"v"(mz1),
          [gx1]"v"(gx1), [gy1]"v"(gy1), [gz1]"v"(gz1),
          [ap]"s"(ap), [an]"s"(an)
        : "s30","s32","s33","s34","s35","s36","s37","s38","s39",
          "s40","s41","s42","s43","s44","s45","s46","s47","s48","s49",
          "s50","s51","s52","s53","s54","s55","s56","s57","s58","s59",
          "s60","s61","s62","s63","s64","s65","s66","s67","s68","s69",
          "s70","s71","s72","s73","s74","s75","s76","s77","s78","s79",
          "s80","s81","s82","s83","s84","s85","s86","s87","s88","s89",
          "s90","s91","s92","s93","s94","s95","s96","s97","s98","s99",
          "scc","vcc","memory");

    float td0[KNN] = {d0_, d1_, d2_, d3_, d4_, d5_, d6_, d7_, d8_, d9_};
    float td1[KNN] = {e0_, e1_, e2_, e3_, e4_, e5_, e6_, e7_, e8_, e9_};

    if (wu > 0) {
#pragma unroll
        for (int j = 0; j < KNN; j++) {
            MRG[wu][lane][j]      = td0[j];
            MRG[wu][lane + 64][j] = td1[j];
        }
    }
    __syncthreads();

    if (wu == 0) {
        // merge the 3 foreign partial top-10 lists for BOTH points
        // (top-k selection is partition-invariant on the value multiset)
#pragma unroll
        for (int ww = 1; ww < NW; ww++) {
#pragma unroll
            for (int j = 0; j < KNN; j++) {
                float cp = MRG[ww][lane][j];
#pragma unroll
                for (int t = KNN - 1; t >= 1; --t)
                    td0[t] = __builtin_amdgcn_fmed3f(td0[t - 1], td0[t], cp);
                td0[0] = fminf(td0[0], cp);
                float cq = MRG[ww][lane + 64][j];
#pragma unroll
                for (int t = KNN - 1; t >= 1; --t)
                    td1[t] = __builtin_amdgcn_fmed3f(td1[t - 1], td1[t], cq);
                td1[0] = fminf(td1[0], cq);
            }
        }

        int cnt0 = 0, cnt1 = 0;
#pragma unroll
        for (int j = 0; j < KNN; j++) {
            cnt0 += (int)(__float_as_uint(td0[j]) & 1u);
            cnt1 += (int)(__float_as_uint(td1[j]) & 1u);
        }
        float dd0 = __uint_as_float(__float_as_uint(td0[0]) & 0xFFFFFFFEu) + xp0.w;
        float r0  = sqrtf(fmaxf(dd0, 0.0f));
        if (cnt0 > 8) r0 = -r0;          // sum(insides) > k*0.8 = 8 -> >= 9
        atomicMin(&SD[b * N_PTS + p0], enc_f(r0));
        float dd1 = __uint_as_float(__float_as_uint(td1[0]) & 0xFFFFFFFEu) + xp1.w;
        float r1  = sqrtf(fmaxf(dd1, 0.0f));
        if (cnt1 > 8) r1 = -r1;
        atomicMin(&SD[b * N_PTS + p1], enc_f(r1));
    }
}

// Kernel 3: decode and emit both outputs (signed_distance, then intersects
// as 0.0/1.0 floats).
__global__ void k_final(const unsigned int* __restrict__ SD,
                       float* __restrict__ out) {
    int gid = blockIdx.x * blockDim.x + threadIdx.x;
    if (gid >= N_OBJ * N_PTS) return;
    float sd = dec_f(SD[gid]);
    out[gid] = sd;
    out[N_OBJ * N_PTS + gid] = (sd < -TOLC) ? 1.0f : 0.0f;
}

extern "C" void kernel_launch(void* const* d_in, const int* in_sizes, int n_in,
                              void* d_out, int out_size, void* d_ws, size_t ws_size,
                              hipStream_t stream) {
    const float* pts     = (const float*)d_in[0];   // (8,2048,6)
    const float* T_est   = (const float*)d_in[1];   // (8,4,4)
    const float* T_plane = (const float*)d_in[2];   // (4,4)
    // d_in[3] is k == 10, hardcoded as KNN

    // workspace layout: P4 (256KB) | N4 (256KB) | SD (64KB)
    float4*       P4 = (float4*)d_ws;
    float4*       N4 = P4 + N_OBJ * N_PTS;
    unsigned int* SD = (unsigned int*)(N4 + N_OBJ * N_PTS);

    float* out = (float*)d_out;

    k_transform<<<(N_OBJ * N_PTS) / 256, 256, 0, stream>>>(pts, T_est, T_plane, P4, N4, SD);
    k_pairs<<<N_OBJ * (N_OBJ - 1) * NCHUNK2, TPB, 0, stream>>>(P4, N4, SD);
    k_final<<<(N_OBJ * N_PTS) / 256, 256, 0, stream>>>(SD, out);
}

// Round 8
// 177.568 us; speedup vs baseline: 1.0050x; 1.0050x over previous
//
#include <hip/hip_runtime.h>
#include <cfloat>
#include <math.h>

#define N_OBJ 8
#define N_PTS 2048
#define KNN   10
#define TOLC  0.01f
#define TPB   256               // k_transform / k_final block size
#define TPB2  512               // k_pairs block size (8 waves)
#define NW8   8                 // waves per k_pairs block = q-split factor
#define QC8   (N_PTS / NW8)     // 256 q's per wave
#define PC2   128               // points per block (2 per lane)
#define NCHUNK2 (N_PTS / PC2)   // 16 point-chunks per pair

// ---- order-preserving float <-> uint for atomicMin on signed floats ----
__device__ __forceinline__ unsigned int enc_f(float f) {
    unsigned int u = __float_as_uint(f);
    return (u & 0x80000000u) ? ~u : (u | 0x80000000u);
}
__device__ __forceinline__ float dec_f(unsigned int e) {
    unsigned int u = (e & 0x80000000u) ? (e & 0x7fffffffu) : ~e;
    return __uint_as_float(u);
}

// Kernel 1: per-point transform (4x4 inverse redundantly in double — closer
// to the numpy reference than fp32 adjugate; trivial cost at 64 waves).
// Writes P4=(x,y,z,|x|^2), N4=(nx,ny,nz,dot(n,x)), SD seed = enc(z).
__global__ void k_transform(const float* __restrict__ pts,
                            const float* __restrict__ T_est,
                            const float* __restrict__ T_plane,
                            float4* __restrict__ P4g,
                            float4* __restrict__ N4g,
                            unsigned int* __restrict__ SD) {
    int gid = blockIdx.x * blockDim.x + threadIdx.x;
    if (gid >= N_OBJ * N_PTS) return;
    int b = gid >> 11;

    double m[16];
#pragma unroll
    for (int i = 0; i < 16; i++) m[i] = (double)T_plane[i];
    double inv[16];
    inv[0]  =  m[5]*m[10]*m[15] - m[5]*m[11]*m[14] - m[9]*m[6]*m[15] + m[9]*m[7]*m[14] + m[13]*m[6]*m[11] - m[13]*m[7]*m[10];
    inv[4]  = -m[4]*m[10]*m[15] + m[4]*m[11]*m[14] + m[8]*m[6]*m[15] - m[8]*m[7]*m[14] - m[12]*m[6]*m[11] + m[12]*m[7]*m[10];
    inv[8]  =  m[4]*m[9]*m[15]  - m[4]*m[11]*m[13] - m[8]*m[5]*m[15] + m[8]*m[7]*m[13] + m[12]*m[5]*m[11] - m[12]*m[7]*m[9];
    inv[12] = -m[4]*m[9]*m[14]  + m[4]*m[10]*m[13] + m[8]*m[5]*m[14] - m[8]*m[6]*m[13] - m[12]*m[5]*m[10] + m[12]*m[6]*m[9];
    inv[1]  = -m[1]*m[10]*m[15] + m[1]*m[11]*m[14] + m[9]*m[2]*m[15] - m[9]*m[3]*m[14] - m[13]*m[2]*m[11] + m[13]*m[3]*m[10];
    inv[5]  =  m[0]*m[10]*m[15] - m[0]*m[11]*m[14] - m[8]*m[2]*m[15] + m[8]*m[3]*m[14] + m[12]*m[2]*m[11] - m[12]*m[3]*m[10];
    inv[9]  = -m[0]*m[9]*m[15]  + m[0]*m[11]*m[13] + m[8]*m[1]*m[15] - m[8]*m[3]*m[13] - m[12]*m[1]*m[11] + m[12]*m[3]*m[9];
    inv[13] =  m[0]*m[9]*m[14]  - m[0]*m[10]*m[13] - m[8]*m[1]*m[14] + m[8]*m[2]*m[13] + m[12]*m[1]*m[10] - m[12]*m[2]*m[9];
    inv[2]  =  m[1]*m[6]*m[15]  - m[1]*m[7]*m[14]  - m[5]*m[2]*m[15] + m[5]*m[3]*m[14] + m[13]*m[2]*m[7]  - m[13]*m[3]*m[6];
    inv[6]  = -m[0]*m[6]*m[15]  + m[0]*m[7]*m[14]  + m[4]*m[2]*m[15] - m[4]*m[3]*m[14] - m[12]*m[2]*m[7]  + m[12]*m[3]*m[6];
    inv[10] =  m[0]*m[5]*m[15]  - m[0]*m[7]*m[13]  - m[4]*m[1]*m[15] + m[4]*m[3]*m[13] + m[12]*m[1]*m[7]  - m[12]*m[3]*m[5];
    inv[14] = -m[0]*m[5]*m[14]  + m[0]*m[6]*m[13]  + m[4]*m[1]*m[14] - m[4]*m[2]*m[13] - m[12]*m[1]*m[6]  + m[12]*m[2]*m[5];
    inv[3]  = -m[1]*m[6]*m[11]  + m[1]*m[7]*m[10]  + m[5]*m[2]*m[11] - m[5]*m[3]*m[10] - m[9]*m[2]*m[7]   + m[9]*m[3]*m[6];
    inv[7]  =  m[0]*m[6]*m[11]  - m[0]*m[7]*m[10]  - m[4]*m[2]*m[11] + m[4]*m[3]*m[10] + m[8]*m[2]*m[7]   - m[8]*m[3]*m[6];
    inv[11] = -m[0]*m[5]*m[11]  + m[0]*m[7]*m[9]   + m[4]*m[1]*m[11] - m[4]*m[3]*m[9]  - m[8]*m[1]*m[7]   + m[8]*m[3]*m[5];
    inv[15] =  m[0]*m[5]*m[10]  - m[0]*m[6]*m[9]   - m[4]*m[1]*m[10] + m[4]*m[2]*m[9]  + m[8]*m[1]*m[6]   - m[8]*m[2]*m[5];
    double det  = m[0]*inv[0] + m[1]*inv[4] + m[2]*inv[8] + m[3]*inv[12];
    double rdet = 1.0 / det;

    const float* Te = T_est + b * 16;
    double M[12];
#pragma unroll
    for (int i = 0; i < 3; i++)
#pragma unroll
        for (int j = 0; j < 4; j++) {
            double s = 0.0;
#pragma unroll
            for (int kk = 0; kk < 4; kk++) s += inv[i*4+kk] * rdet * (double)Te[kk*4+j];
            M[i*4+j] = s;
        }

    const float* pp = pts + (size_t)gid * 6;
    double px = pp[0], py = pp[1], pz = pp[2];
    float nx = pp[3], ny = pp[4], nz = pp[5];
    float x = (float)(M[0]*px + M[1]*py + M[2]*pz  + M[3]);
    float y = (float)(M[4]*px + M[5]*py + M[6]*pz  + M[7]);
    float z = (float)(M[8]*px + M[9]*py + M[10]*pz + M[11]);
    float sq = fmaf(x, x, fmaf(y, y, z * z));
    float w  = fmaf(nx, x, fmaf(ny, y, nz * z));
    P4g[gid] = make_float4(x, y, z, sq);
    N4g[gid] = make_float4(nx, ny, nz, w);
    SD[gid]  = enc_f(z);   // seed min with the plane-distance term z
}

// One q against TWO points per lane: 44 VALU ops. Per-p op order is IDENTICAL
// to rounds 0-7 (bit-identical numerics); the p0/p1 chains are interleaved for
// ILP. Q data comes from SGPRs (broadcast, shared by both p's); <=1 SGPR per
// VALU inst (SGPR in src0 for VOP2, src1 for VOP3 fma).
#define QB2(PX,PY,PZ,PW,NX,NY,NZ,NWW) \
  "v_mul_f32 %[t0], " PZ ", %[mz0]\n" \
  "v_mul_f32 %[t2], " PZ ", %[mz1]\n" \
  "v_fma_f32 %[t0], %[my0], " PY ", %[t0]\n" \
  "v_fma_f32 %[t2], %[my1], " PY ", %[t2]\n" \
  "v_fma_f32 %[t0], %[mx0], " PX ", %[t0]\n" \
  "v_fma_f32 %[t2], %[mx1], " PX ", %[t2]\n" \
  "v_add_f32 %[t0], " PW ", %[t0]\n" \
  "v_add_f32 %[t2], " PW ", %[t2]\n" \
  "v_mul_f32 %[t1], " NZ ", %[gz0]\n" \
  "v_mul_f32 %[t3], " NZ ", %[gz1]\n" \
  "v_fma_f32 %[t1], %[gy0], " NY ", %[t1]\n" \
  "v_fma_f32 %[t3], %[gy1], " NY ", %[t3]\n" \
  "v_fma_f32 %[t1], %[gx0], " NX ", %[t1]\n" \
  "v_fma_f32 %[t3], %[gx1], " NX ", %[t3]\n" \
  "v_add_f32 %[t1], " NWW ", %[t1]\n" \
  "v_add_f32 %[t3], " NWW ", %[t3]\n" \
  "v_and_b32 %[t0], -2, %[t0]\n" \
  "v_and_b32 %[t2], -2, %[t2]\n" \
  "v_cmp_lt_f32 vcc, 0, %[t1]\n" \
  "v_cndmask_b32_e64 %[t1], 0, 1, vcc\n" \
  "v_or_b32 %[t0], %[t0], %[t1]\n" \
  "v_cmp_lt_f32 vcc, 0, %[t3]\n" \
  "v_cndmask_b32_e64 %[t3], 0, 1, vcc\n" \
  "v_or_b32 %[t2], %[t2], %[t3]\n" \
  "v_med3_f32 %[d9], %[d8], %[d9], %[t0]\n" \
  "v_med3_f32 %[d8], %[d7], %[d8], %[t0]\n" \
  "v_med3_f32 %[d7], %[d6], %[d7], %[t0]\n" \
  "v_med3_f32 %[d6], %[d5], %[d6], %[t0]\n" \
  "v_med3_f32 %[d5], %[d4], %[d5], %[t0]\n" \
  "v_med3_f32 %[d4], %[d3], %[d4], %[t0]\n" \
  "v_med3_f32 %[d3], %[d2], %[d3], %[t0]\n" \
  "v_med3_f32 %[d2], %[d1], %[d2], %[t0]\n" \
  "v_med3_f32 %[d1], %[d0], %[d1], %[t0]\n" \
  "v_min_f32 %[d0], %[d0], %[t0]\n" \
  "v_med3_f32 %[e9], %[e8], %[e9], %[t2]\n" \
  "v_med3_f32 %[e8], %[e7], %[e8], %[t2]\n" \
  "v_med3_f32 %[e7], %[e6], %[e7], %[t2]\n" \
  "v_med3_f32 %[e6], %[e5], %[e6], %[t2]\n" \
  "v_med3_f32 %[e5], %[e4], %[e5], %[t2]\n" \
  "v_med3_f32 %[e4], %[e3], %[e4], %[t2]\n" \
  "v_med3_f32 %[e3], %[e2], %[e3], %[t2]\n" \
  "v_med3_f32 %[e2], %[e1], %[e2], %[t2]\n" \
  "v_med3_f32 %[e1], %[e0], %[e1], %[t2]\n" \
  "v_min_f32 %[e0], %[e0], %[t2]\n"

// Kernel 2 v8: r7's 2-points-per-lane q-sharing (halved SMEM lines) + 8-wave
// blocks to restore the outstanding-s_load population.
// Model (r4+r7, Little's law): scalar supply ~ outstanding/4300cy; r4 had 112
// outstanding -> 0.026 lines/cy (line-bound at 7168 lines/CU = 114us); r7 had
// 56 -> 0.013 (3584 lines = its 136us wall). This kernel: 3584 lines/CU AND
// ~96-112 outstanding (24-28 waves/CU x 4) -> line-wall ~160K cy ~= the VALU
// floor (158K cy/SIMD) instead of 2.4x above it.
// 8-way q split x 256 q/wave, same 128 p per block; top-k is partition-
// invariant; 7-list LDS merge. QB2 body untouched (bit-identical numerics).
__global__ void __launch_bounds__(TPB2, 7) k_pairs(const float4* __restrict__ P4g,
                                                   const float4* __restrict__ N4g,
                                                   unsigned int* __restrict__ SD) {
    // stride 11 floats: 11 coprime 32 -> 2 lanes/bank, conflict-free. 39424B.
    __shared__ float MRG[NW8 - 1][PC2][KNN + 1];

    int bx    = blockIdx.x;
    int pair  = bx >> 4;           // / NCHUNK2
    int chunk = bx & (NCHUNK2 - 1);
    int b  = pair / 7;
    int oi = pair % 7;
    int o  = oi + (oi >= b ? 1 : 0);
    int tid  = threadIdx.x;
    int lane = tid & 63;
    int wu   = __builtin_amdgcn_readfirstlane(tid >> 6);   // 0..7
    int p0   = chunk * PC2 + lane;
    int p1   = p0 + 64;

    float4 xp0 = P4g[b * N_PTS + p0];        // (x, y, z, sq_p)
    float4 xp1 = P4g[b * N_PTS + p1];
    float mx0 = -2.0f * xp0.x, my0 = -2.0f * xp0.y, mz0 = -2.0f * xp0.z;
    float gx0 = -xp0.x, gy0 = -xp0.y, gz0 = -xp0.z;
    float mx1 = -2.0f * xp1.x, my1 = -2.0f * xp1.y, mz1 = -2.0f * xp1.z;
    float gx1 = -xp1.x, gy1 = -xp1.y, gz1 = -xp1.z;

    const float4* Po = P4g + o * N_PTS + wu * QC8;  // uniform stream bases
    const float4* No = N4g + o * N_PTS + wu * QC8;
    unsigned long long ap = (unsigned long long)(uintptr_t)Po;
    unsigned long long an = (unsigned long long)(uintptr_t)No;

    const float FMAXE = __uint_as_float(0x7F7FFFFEu);   // FLT_MAX, LSB clear
    float d0_ = FMAXE, d1_ = FMAXE, d2_ = FMAXE, d3_ = FMAXE, d4_ = FMAXE;
    float d5_ = FMAXE, d6_ = FMAXE, d7_ = FMAXE, d8_ = FMAXE, d9_ = FMAXE;
    float e0_ = FMAXE, e1_ = FMAXE, e2_ = FMAXE, e3_ = FMAXE, e4_ = FMAXE;
    float e5_ = FMAXE, e6_ = FMAXE, e7_ = FMAXE, e8_ = FMAXE, e9_ = FMAXE;
    float t0, t1, t2, t3;

    // Double-banked SGPR q-buffers: bank A s[36:67] (P s[36:51], N s[52:67]),
    // bank B s[68:99]. 4 q per bank. 32 iters x 8 q = 256 q.
    // Last prefetch reads <=128B past the window: stays inside P4|N4|SD for
    // every (o,wu) incl. the worst case o=7,wu=7 (runs into SD, harmless).
    asm volatile(
        "s_mov_b64 s[32:33], %[ap]\n"
        "s_mov_b64 s[34:35], %[an]\n"
        "s_load_dwordx16 s[36:51], s[32:33], 0x0\n"
        "s_load_dwordx16 s[52:67], s[34:35], 0x0\n"
        "s_mov_b32 s30, 0\n"
        "Lkp%=:\n"
        "s_waitcnt lgkmcnt(0)\n"                         // bank A ready
        "s_load_dwordx16 s[68:83], s[32:33], 0x40\n"     // prefetch bank B
        "s_load_dwordx16 s[84:99], s[34:35], 0x40\n"
        QB2("s36","s37","s38","s39","s52","s53","s54","s55")
        QB2("s40","s41","s42","s43","s56","s57","s58","s59")
        QB2("s44","s45","s46","s47","s60","s61","s62","s63")
        QB2("s48","s49","s50","s51","s64","s65","s66","s67")
        "s_waitcnt lgkmcnt(0)\n"                         // bank B ready
        "s_load_dwordx16 s[36:51], s[32:33], 0x80\n"     // prefetch next A
        "s_load_dwordx16 s[52:67], s[34:35], 0x80\n"
        QB2("s68","s69","s70","s71","s84","s85","s86","s87")
        QB2("s72","s73","s74","s75","s88","s89","s90","s91")
        QB2("s76","s77","s78","s79","s92","s93","s94","s95")
        QB2("s80","s81","s82","s83","s96","s97","s98","s99")
        "s_add_u32 s32, s32, 0x80\n"
        "s_addc_u32 s33, s33, 0\n"
        "s_add_u32 s34, s34, 0x80\n"
        "s_addc_u32 s35, s35, 0\n"
        "s_add_u32 s30, s30, 1\n"
        "s_cmp_lt_u32 s30, 32\n"
        "s_cbranch_scc1 Lkp%=\n"
        "s_waitcnt lgkmcnt(0)\n"   // drain dangling prefetch before reg reuse
        : [d0]"+v"(d0_), [d1]"+v"(d1_), [d2]"+v"(d2_), [d3]"+v"(d3_),
          [d4]"+v"(d4_), [d5]"+v"(d5_), [d6]"+v"(d6_), [d7]"+v"(d7_),
          [d8]"+v"(d8_), [d9]"+v"(d9_),
          [e0]"+v"(e0_), [e1]"+v"(e1_), [e2]"+v"(e2_), [e3]"+v"(e3_),
          [e4]"+v"(e4_), [e5]"+v"(e5_), [e6]"+v"(e6_), [e7]"+v"(e7_),
          [e8]"+v"(e8_), [e9]"+v"(e9_),
          [t0]"=&v"(t0), [t1]"=&v"(t1), [t2]"=&v"(t2), [t3]"=&v"(t3)
        : [mx0]"v"(mx0), [my0]"v"(my0), [mz0]"v"(mz0),
          [gx0]"v"(gx0), [gy0]"v"(gy0), [gz0]"v"(gz0),
          [mx1]"v"(mx1), [my1]"v"(my1), [mz1]"v"(mz1),
          [gx1]"v"(gx1), [gy1]"v"(gy1), [gz1]"v"(gz1),
          [ap]"s"(ap), [an]"s"(an)
        : "s30","s32","s33","s34","s35","s36","s37","s38","s39",
          "s40","s41","s42","s43","s44","s45","s46","s47","s48","s49",
          "s50","s51","s52","s53","s54","s55","s56","s57","s58","s59",
          "s60","s61","s62","s63","s64","s65","s66","s67","s68","s69",
          "s70","s71","s72","s73","s74","s75","s76","s77","s78","s79",
          "s80","s81","s82","s83","s84","s85","s86","s87","s88","s89",
          "s90","s91","s92","s93","s94","s95","s96","s97","s98","s99",
          "scc","vcc","memory");

    float td0[KNN] = {d0_, d1_, d2_, d3_, d4_, d5_, d6_, d7_, d8_, d9_};
    float td1[KNN] = {e0_, e1_, e2_, e3_, e4_, e5_, e6_, e7_, e8_, e9_};

    if (wu > 0) {
#pragma unroll
        for (int j = 0; j < KNN; j++) {
            MRG[wu - 1][lane][j]      = td0[j];
            MRG[wu - 1][lane + 64][j] = td1[j];
        }
    }
    __syncthreads();

    if (wu == 0) {
        // merge the 7 foreign partial top-10 lists for BOTH points
        // (top-k selection is partition-invariant on the value multiset)
#pragma unroll
        for (int ww = 0; ww < NW8 - 1; ww++) {
#pragma unroll
            for (int j = 0; j < KNN; j++) {
                float cp = MRG[ww][lane][j];
#pragma unroll
                for (int t = KNN - 1; t >= 1; --t)
                    td0[t] = __builtin_amdgcn_fmed3f(td0[t - 1], td0[t], cp);
                td0[0] = fminf(td0[0], cp);
                float cq = MRG[ww][lane + 64][j];
#pragma unroll
                for (int t = KNN - 1; t >= 1; --t)
                    td1[t] = __builtin_amdgcn_fmed3f(td1[t - 1], td1[t], cq);
                td1[0] = fminf(td1[0], cq);
            }
        }

        int cnt0 = 0, cnt1 = 0;
#pragma unroll
        for (int j = 0; j < KNN; j++) {
            cnt0 += (int)(__float_as_uint(td0[j]) & 1u);
            cnt1 += (int)(__float_as_uint(td1[j]) & 1u);
        }
        float dd0 = __uint_as_float(__float_as_uint(td0[0]) & 0xFFFFFFFEu) + xp0.w;
        float r0  = sqrtf(fmaxf(dd0, 0.0f));
        if (cnt0 > 8) r0 = -r0;          // sum(insides) > k*0.8 = 8 -> >= 9
        atomicMin(&SD[b * N_PTS + p0], enc_f(r0));
        float dd1 = __uint_as_float(__float_as_uint(td1[0]) & 0xFFFFFFFEu) + xp1.w;
        float r1  = sqrtf(fmaxf(dd1, 0.0f));
        if (cnt1 > 8) r1 = -r1;
        atomicMin(&SD[b * N_PTS + p1], enc_f(r1));
    }
}

// Kernel 3: decode and emit both outputs (signed_distance, then intersects
// as 0.0/1.0 floats).
__global__ void k_final(const unsigned int* __restrict__ SD,
                       float* __restrict__ out) {
    int gid = blockIdx.x * blockDim.x + threadIdx.x;
    if (gid >= N_OBJ * N_PTS) return;
    float sd = dec_f(SD[gid]);
    out[gid] = sd;
    out[N_OBJ * N_PTS + gid] = (sd < -TOLC) ? 1.0f : 0.0f;
}

extern "C" void kernel_launch(void* const* d_in, const int* in_sizes, int n_in,
                              void* d_out, int out_size, void* d_ws, size_t ws_size,
                              hipStream_t stream) {
    const float* pts     = (const float*)d_in[0];   // (8,2048,6)
    const float* T_est   = (const float*)d_in[1];   // (8,4,4)
    const float* T_plane = (const float*)d_in[2];   // (4,4)
    // d_in[3] is k == 10, hardcoded as KNN

    // workspace layout: P4 (256KB) | N4 (256KB) | SD (64KB)
    float4*       P4 = (float4*)d_ws;
    float4*       N4 = P4 + N_OBJ * N_PTS;
    unsigned int* SD = (unsigned int*)(N4 + N_OBJ * N_PTS);

    float* out = (float*)d_out;

    k_transform<<<(N_OBJ * N_PTS) / TPB, TPB, 0, stream>>>(pts, T_est, T_plane, P4, N4, SD);
    k_pairs<<<N_OBJ * (N_OBJ - 1) * NCHUNK2, TPB2, 0, stream>>>(P4, N4, SD);
    k_final<<<(N_OBJ * N_PTS) / TPB, TPB, 0, stream>>>(SD, out);
}